// Round 3
// baseline (851.448 us; speedup 1.0000x reference)
//
#include <hip/hip_runtime.h>
#include <cstddef>
#include <cstdint>

#define BB 4
#define SS 2048
#define EE 1024
#define HH 16
#define DD 64
#define FF 4096

typedef unsigned short u16;
typedef __attribute__((ext_vector_type(8))) short short8;   // 8 bf16 = 4 VGPR (MFMA A/B frag)
typedef __attribute__((ext_vector_type(4))) short short4v;
typedef __attribute__((ext_vector_type(4))) float f32x4;    // MFMA C/D frag

__device__ __forceinline__ u16 f2bf(float x) {
    unsigned u = __builtin_bit_cast(unsigned, x);
    u += 0x7fffu + ((u >> 16) & 1u);   // round-to-nearest-even
    return (u16)(u >> 16);
}
__device__ __forceinline__ float bf2f(u16 h) {
    unsigned u = ((unsigned)h) << 16;
    return __builtin_bit_cast(float, u);
}

// async global->LDS DMA, 16B per lane; LDS dest must be wave-uniform base
#define GLD_LDS16(g, l)                                                     \
    __builtin_amdgcn_global_load_lds(                                       \
        (const __attribute__((address_space(1))) void*)(g),                 \
        (__attribute__((address_space(3))) void*)(l), 16, 0, 0)

// ---------------------------------------------------------------------------
// fp32 -> bf16 elementwise convert (4 elems/thread)
// ---------------------------------------------------------------------------
__global__ __launch_bounds__(256) void cvt_bf(const float* __restrict__ in,
                                              u16* __restrict__ out, int n4) {
    const int i = blockIdx.x * 256 + threadIdx.x;
    if (i < n4) {
        float4 v = reinterpret_cast<const float4*>(in)[i];
        short4v o;
        o.x = (short)f2bf(v.x); o.y = (short)f2bf(v.y);
        o.z = (short)f2bf(v.z); o.w = (short)f2bf(v.w);
        reinterpret_cast<short4v*>(out)[i] = o;
    }
}

// ---------------------------------------------------------------------------
// Transpose + convert: out[c][r] = (bf16) in[r][c].  in: [R][C] fp32, batched.
// grid (R/64, C/64, batch)
// ---------------------------------------------------------------------------
__global__ __launch_bounds__(256) void transp_bf(const float* __restrict__ in,
                                                 u16* __restrict__ out, int R, int C) {
    __shared__ float T[64][65];
    const int r0 = blockIdx.x * 64, c0 = blockIdx.y * 64;
    const size_t zoff = (size_t)blockIdx.z * R * C;
    in += zoff; out += zoff;
    const int tid = threadIdx.x;
#pragma unroll 4
    for (int i = 0; i < 16; ++i) {
        int l = tid + i * 256;
        T[l >> 6][l & 63] = in[(size_t)(r0 + (l >> 6)) * C + c0 + (l & 63)];
    }
    __syncthreads();
#pragma unroll 4
    for (int i = 0; i < 16; ++i) {
        int l = tid + i * 256;
        out[(size_t)(c0 + (l >> 6)) * R + r0 + (l & 63)] = f2bf(T[l & 63][l >> 6]);
    }
}

// ---------------------------------------------------------------------------
// bf16 MFMA GEMM, 128x128 tile, BK=32, 4 waves (each a 64x64 quadrant).
// m97 pattern: async global_load_lds staging, unpadded [128][32] LDS tiles.
// A [M][K] bf16 row-major (k inner); BT [N][K] bf16 (k inner). C row-major ldc=N.
// EPI: 0 = bf16 out | 1 = f32 out + f32 resid | 2 = bf16 out + bias + relu
//      3 = f32 out + bias + bf16 resid
// ---------------------------------------------------------------------------
template <int EPI>
__global__ __launch_bounds__(256) void gemm_bf16(const u16* __restrict__ A,
                                                 const u16* __restrict__ BT,
                                                 int K, int N,
                                                 void* __restrict__ Cout,
                                                 const float* __restrict__ bias,
                                                 const void* __restrict__ resid) {
    __shared__ u16 As[128 * 32];
    __shared__ u16 Bs[128 * 32];
    const int tid = threadIdx.x;
    const int w = tid >> 6, l = tid & 63;
    const int quad = l >> 4, lane16 = l & 15;
    const int wr = (w >> 1) * 64, wc = (w & 1) * 64;
    const int m0 = blockIdx.x * 128, n0 = blockIdx.y * 128;
    // DMA source: lane l covers row (w*32 + c*16 + l/4), k-chunk (l&3)*8
    const int drow = w * 32 + (l >> 2);
    const int dk = (l & 3) * 8;
    const u16* Ag = A + (size_t)(m0 + drow) * K + dk;
    const u16* Bg = BT + (size_t)(n0 + drow) * K + dk;
    const size_t r16 = (size_t)16 * K;
    u16* AsD = &As[w * 1024];   // wave-uniform; HW adds lane*16B
    u16* BsD = &Bs[w * 1024];

    f32x4 acc[4][4] = {};
    for (int k0 = 0; k0 < K; k0 += 32) {
        __syncthreads();
        GLD_LDS16(Ag + k0, AsD);
        GLD_LDS16(Ag + k0 + r16, AsD + 512);
        GLD_LDS16(Bg + k0, BsD);
        GLD_LDS16(Bg + k0 + r16, BsD + 512);
        __syncthreads();   // drains vmcnt(0): DMA data visible
        short8 af[4], bf[4];
#pragma unroll
        for (int mf = 0; mf < 4; ++mf)
            af[mf] = *(const short8*)&As[(wr + mf * 16 + lane16) * 32 + quad * 8];
#pragma unroll
        for (int nf = 0; nf < 4; ++nf)
            bf[nf] = *(const short8*)&Bs[(wc + nf * 16 + lane16) * 32 + quad * 8];
#pragma unroll
        for (int mf = 0; mf < 4; ++mf)
#pragma unroll
            for (int nf = 0; nf < 4; ++nf)
                acc[mf][nf] = __builtin_amdgcn_mfma_f32_16x16x32_bf16(af[mf], bf[nf], acc[mf][nf], 0, 0, 0);
    }

#pragma unroll
    for (int mf = 0; mf < 4; ++mf) {
        const int row = m0 + wr + mf * 16 + quad * 4;
#pragma unroll
        for (int nf = 0; nf < 4; ++nf) {
            const int col = n0 + wc + nf * 16 + lane16;
#pragma unroll
            for (int r = 0; r < 4; ++r) {
                float v = acc[mf][nf][r];
                const size_t idx = (size_t)(row + r) * N + col;
                if (EPI == 0) {
                    ((u16*)Cout)[idx] = f2bf(v);
                } else if (EPI == 1) {
                    ((float*)Cout)[idx] = v + ((const float*)resid)[idx];
                } else if (EPI == 2) {
                    v += bias[col];
                    ((u16*)Cout)[idx] = f2bf(fmaxf(v, 0.f));
                } else {
                    v += bias[col] + bf2f(((const u16*)resid)[idx]);
                    ((float*)Cout)[idx] = v;
                }
            }
        }
    }
}

// ---------------------------------------------------------------------------
// Pass 1: column-softmax stats via MFMA. Q,K: [B,S,H*D] bf16.
// Block = 128 t-cols x bh. K B-frags loop-invariant -> registers; only Q in LDS.
// Wave w owns t in [t0+w*32, +32). C-frag col = t -> per-lane online (m,l),
// then cross-quad shfl combine. grid (S/128, B*H)
// ---------------------------------------------------------------------------
__global__ __launch_bounds__(256) void stats_mfma(const u16* __restrict__ Qg,
                                                  const u16* __restrict__ Kg,
                                                  float* __restrict__ Ms,
                                                  float* __restrict__ Ls) {
    __shared__ u16 Qt[64 * 72];   // [s][d], +8 pad
    const int t0 = blockIdx.x * 128;
    const int bh = blockIdx.y;
    const int b = bh >> 4, h = bh & 15;
    const int tid = threadIdx.x;
    const int w = tid >> 6, l = tid & 63;
    const int quad = l >> 4, lane16 = l & 15;
    const u16* Qp = Qg + (size_t)b * SS * 1024 + h * 64;
    const u16* Kp = Kg + (size_t)b * SS * 1024 + h * 64;
    const int sr = tid >> 3;            // 0..31
    const int dg = (tid & 7) * 8;

    // K as B-operand frags in registers: lane n=t holds K[t][d=ks*32+quad*8..+7]
    short8 kf[2][2];
#pragma unroll
    for (int nf = 0; nf < 2; ++nf)
#pragma unroll
        for (int ks = 0; ks < 2; ++ks)
            kf[nf][ks] = *(const short8*)(Kp +
                (size_t)(t0 + w * 32 + nf * 16 + lane16) * 1024 + ks * 32 + quad * 8);

    float mcol[2] = {-1e30f, -1e30f};
    float lcol[2] = {0.f, 0.f};
    for (int st = 0; st < 32; ++st) {
        __syncthreads();
        const u16* qsrc = Qp + (size_t)(st * 64 + sr) * 1024 + dg;
        *(short8*)&Qt[sr * 72 + dg] = *(const short8*)qsrc;
        *(short8*)&Qt[(sr + 32) * 72 + dg] = *(const short8*)(qsrc + (size_t)32 * 1024);
        __syncthreads();
        f32x4 sc[4][2] = {};
#pragma unroll
        for (int ks = 0; ks < 2; ++ks) {
#pragma unroll
            for (int mf = 0; mf < 4; ++mf) {
                short8 afr = *(const short8*)&Qt[(mf * 16 + lane16) * 72 + ks * 32 + quad * 8];
#pragma unroll
                for (int nf = 0; nf < 2; ++nf)
                    sc[mf][nf] = __builtin_amdgcn_mfma_f32_16x16x32_bf16(afr, kf[nf][ks], sc[mf][nf], 0, 0, 0);
            }
        }
#pragma unroll
        for (int nf = 0; nf < 2; ++nf) {
            float tmax = -1e30f;
#pragma unroll
            for (int mf = 0; mf < 4; ++mf)
#pragma unroll
                for (int r = 0; r < 4; ++r) tmax = fmaxf(tmax, sc[mf][nf][r]);
            const float nm = fmaxf(mcol[nf], tmax);
            float add = 0.f;
#pragma unroll
            for (int mf = 0; mf < 4; ++mf)
#pragma unroll
                for (int r = 0; r < 4; ++r) add += __expf(sc[mf][nf][r] - nm);
            lcol[nf] = lcol[nf] * __expf(mcol[nf] - nm) + add;
            mcol[nf] = nm;
        }
    }
#pragma unroll
    for (int nf = 0; nf < 2; ++nf) {
#pragma unroll
        for (int off = 32; off >= 16; off >>= 1) {
            float om = __shfl_xor(mcol[nf], off);
            float ol = __shfl_xor(lcol[nf], off);
            float nm = fmaxf(mcol[nf], om);
            lcol[nf] = lcol[nf] * __expf(mcol[nf] - nm) + ol * __expf(om - nm);
            mcol[nf] = nm;
        }
        if (quad == 0) {
            Ms[(size_t)bh * SS + t0 + w * 32 + nf * 16 + lane16] = mcol[nf];
            Ls[(size_t)bh * SS + t0 + w * 32 + nf * 16 + lane16] = lcol[nf];
        }
    }
}

// ---------------------------------------------------------------------------
// Pass 2: S^T = K @ Q^T (Q B-frags in registers), normalize with column stats
// (4 consecutive t per C-frag -> packed b64 stores into Ps[s][t]), then
// O = P @ V via MFMA. Vt global: [H*D][B*S] bf16 (t contiguous).
// Output written straight into att_vec layout [B,S,H*D] bf16.
// grid (S/128, B*H)
// ---------------------------------------------------------------------------
__global__ __launch_bounds__(256) void pv_mfma(const u16* __restrict__ Qg,
                                               const u16* __restrict__ Kg,
                                               const u16* __restrict__ Vtg,
                                               const float* __restrict__ Ms,
                                               const float* __restrict__ Ls,
                                               u16* __restrict__ vecbf) {
    __shared__ u16 Ks[64 * 72];   // [t][d], +8 pad
    __shared__ u16 Vs[64 * 72];   // [d][t], +8 pad
    __shared__ u16 Ps[128 * 68];  // [s][t], +4 pad (2-way banks = free)
    const int s0 = blockIdx.x * 128;
    const int bh = blockIdx.y;
    const int b = bh >> 4, h = bh & 15;
    const int tid = threadIdx.x;
    const int w = tid >> 6, l = tid & 63;
    const int quad = l >> 4, lane16 = l & 15;
    const u16* Qp = Qg + (size_t)b * SS * 1024 + h * 64;
    const u16* Kp = Kg + (size_t)b * SS * 1024 + h * 64;
    const u16* Vp = Vtg + (size_t)h * 64 * 8192 + (size_t)b * SS;
    const float* Msb = Ms + (size_t)bh * SS;
    const float* Lsb = Ls + (size_t)bh * SS;
    const int sr = tid >> 3, dg = (tid & 7) * 8;

    // Q as B-operand frags in registers (loop-invariant):
    // lane n=s holds Q[s0+w*32+nf*16+lane16][d=ks*32+quad*8..+7]
    short8 qf[2][2];
#pragma unroll
    for (int nf = 0; nf < 2; ++nf)
#pragma unroll
        for (int ks = 0; ks < 2; ++ks)
            qf[nf][ks] = *(const short8*)(Qp +
                (size_t)(s0 + w * 32 + nf * 16 + lane16) * 1024 + ks * 32 + quad * 8);

    f32x4 acc[2][4] = {};
    for (int tt = 0; tt < 32; ++tt) {
        const int t0 = tt * 64;
        __syncthreads();   // all waves done reading Ks/Vs of prev iter
        *(short8*)&Ks[sr * 72 + dg] = *(const short8*)(Kp + (size_t)(t0 + sr) * 1024 + dg);
        *(short8*)&Ks[(sr + 32) * 72 + dg] = *(const short8*)(Kp + (size_t)(t0 + sr + 32) * 1024 + dg);
        *(short8*)&Vs[sr * 72 + dg] = *(const short8*)(Vp + (size_t)sr * 8192 + t0 + dg);
        *(short8*)&Vs[(sr + 32) * 72 + dg] = *(const short8*)(Vp + (size_t)(sr + 32) * 8192 + t0 + dg);
        __syncthreads();
        // ---- S^T = K-tile (A, m=t 64 rows) @ Q^T (B regs, n=s wave's 32)
        f32x4 sc[4][2] = {};
#pragma unroll
        for (int ks = 0; ks < 2; ++ks) {
#pragma unroll
            for (int mf = 0; mf < 4; ++mf) {
                short8 afr = *(const short8*)&Ks[(mf * 16 + lane16) * 72 + ks * 32 + quad * 8];
#pragma unroll
                for (int nf = 0; nf < 2; ++nf)
                    sc[mf][nf] = __builtin_amdgcn_mfma_f32_16x16x32_bf16(afr, qf[nf][ks], sc[mf][nf], 0, 0, 0);
            }
        }
        // ---- normalize; C-frag rows = 4 consecutive t -> pack one b64 store
#pragma unroll
        for (int mf = 0; mf < 4; ++mf) {
            const int tb = t0 + mf * 16 + quad * 4;
            float4 m4 = *(const float4*)(Msb + tb);
            float4 l4 = *(const float4*)(Lsb + tb);
            const float rl0 = 0.125f / l4.x, rl1 = 0.125f / l4.y;
            const float rl2 = 0.125f / l4.z, rl3 = 0.125f / l4.w;
#pragma unroll
            for (int nf = 0; nf < 2; ++nf) {
                const int srow = w * 32 + nf * 16 + lane16;
                short4v pk;
                pk.x = (short)f2bf(__expf(sc[mf][nf][0] - m4.x) * rl0);
                pk.y = (short)f2bf(__expf(sc[mf][nf][1] - m4.y) * rl1);
                pk.z = (short)f2bf(__expf(sc[mf][nf][2] - m4.z) * rl2);
                pk.w = (short)f2bf(__expf(sc[mf][nf][3] - m4.w) * rl3);
                *(short4v*)&Ps[srow * 68 + mf * 16 + quad * 4] = pk;
            }
        }
        // ---- PV: Ps rows [w*32, w*32+32) are wave-local -> no barrier
#pragma unroll
        for (int ks = 0; ks < 2; ++ks) {
            short8 bfr[4];
#pragma unroll
            for (int nf = 0; nf < 4; ++nf)
                bfr[nf] = *(const short8*)&Vs[(nf * 16 + lane16) * 72 + ks * 32 + quad * 8];
            short8 afr[2];
#pragma unroll
            for (int mf = 0; mf < 2; ++mf)
                afr[mf] = *(const short8*)&Ps[(w * 32 + mf * 16 + lane16) * 68 + ks * 32 + quad * 8];
#pragma unroll
            for (int mf = 0; mf < 2; ++mf)
#pragma unroll
                for (int nf = 0; nf < 4; ++nf)
                    acc[mf][nf] = __builtin_amdgcn_mfma_f32_16x16x32_bf16(afr[mf], bfr[nf], acc[mf][nf], 0, 0, 0);
        }
    }
#pragma unroll
    for (int mf = 0; mf < 2; ++mf)
#pragma unroll
        for (int nf = 0; nf < 4; ++nf) {
            const int col = h * 64 + nf * 16 + lane16;
#pragma unroll
            for (int r = 0; r < 4; ++r) {
                const int srow = s0 + w * 32 + mf * 16 + quad * 4 + r;
                vecbf[(size_t)(b * SS + srow) * 1024 + col] = f2bf(acc[mf][nf][r]);
            }
        }
}

// ---------------------------------------------------------------------------
// LayerNorm over last dim (E=1024), fp32 in -> bf16 out (separate buffer)
// ---------------------------------------------------------------------------
__global__ __launch_bounds__(256) void ln_bf_kernel(const float* __restrict__ buf,
                                                    const float* __restrict__ g,
                                                    const float* __restrict__ be,
                                                    u16* __restrict__ outbf) {
    const int row = blockIdx.x;
    const int tid = threadIdx.x;
    const float* p = buf + (size_t)row * EE;
    float4 x = reinterpret_cast<const float4*>(p)[tid];
    float s = x.x + x.y + x.z + x.w;
    __shared__ float red[4];
#pragma unroll
    for (int o = 32; o > 0; o >>= 1) s += __shfl_down(s, o);
    const int wid = tid >> 6, lane = tid & 63;
    if (lane == 0) red[wid] = s;
    __syncthreads();
    const float mu = (red[0] + red[1] + red[2] + red[3]) * (1.0f / EE);
    __syncthreads();
    const float dx = x.x - mu, dy = x.y - mu, dz = x.z - mu, dw = x.w - mu;
    float v = dx * dx + dy * dy + dz * dz + dw * dw;
#pragma unroll
    for (int o = 32; o > 0; o >>= 1) v += __shfl_down(v, o);
    if (lane == 0) red[wid] = v;
    __syncthreads();
    const float var = (red[0] + red[1] + red[2] + red[3]) * (1.0f / EE);
    const float rs = rsqrtf(var + 1e-5f);
    float4 gv = reinterpret_cast<const float4*>(g)[tid];
    float4 bv = reinterpret_cast<const float4*>(be)[tid];
    short4v o;
    o.x = (short)f2bf(dx * rs * gv.x + bv.x);
    o.y = (short)f2bf(dy * rs * gv.y + bv.y);
    o.z = (short)f2bf(dz * rs * gv.z + bv.z);
    o.w = (short)f2bf(dw * rs * gv.w + bv.w);
    reinterpret_cast<short4v*>(outbf + (size_t)row * EE)[tid] = o;
}

// In-place fp32 LayerNorm (final output)
__global__ __launch_bounds__(256) void ln_kernel(float* __restrict__ buf,
                                                 const float* __restrict__ g,
                                                 const float* __restrict__ be) {
    const int row = blockIdx.x;
    const int tid = threadIdx.x;
    float* p = buf + (size_t)row * EE;
    float4 x = reinterpret_cast<float4*>(p)[tid];
    float s = x.x + x.y + x.z + x.w;
    __shared__ float red[4];
#pragma unroll
    for (int o = 32; o > 0; o >>= 1) s += __shfl_down(s, o);
    const int wid = tid >> 6, lane = tid & 63;
    if (lane == 0) red[wid] = s;
    __syncthreads();
    const float mu = (red[0] + red[1] + red[2] + red[3]) * (1.0f / EE);
    __syncthreads();
    const float dx = x.x - mu, dy = x.y - mu, dz = x.z - mu, dw = x.w - mu;
    float v = dx * dx + dy * dy + dz * dz + dw * dw;
#pragma unroll
    for (int o = 32; o > 0; o >>= 1) v += __shfl_down(v, o);
    if (lane == 0) red[wid] = v;
    __syncthreads();
    const float var = (red[0] + red[1] + red[2] + red[3]) * (1.0f / EE);
    const float rs = rsqrtf(var + 1e-5f);
    float4 gv = reinterpret_cast<const float4*>(g)[tid];
    float4 bv = reinterpret_cast<const float4*>(be)[tid];
    float4 y;
    y.x = dx * rs * gv.x + bv.x;
    y.y = dy * rs * gv.y + bv.y;
    y.z = dz * rs * gv.z + bv.z;
    y.w = dw * rs * gv.w + bv.w;
    reinterpret_cast<float4*>(p)[tid] = y;
}

// ---------------------------------------------------------------------------
extern "C" void kernel_launch(void* const* d_in, const int* in_sizes, int n_in,
                              void* d_out, int out_size, void* d_ws, size_t ws_size,
                              hipStream_t stream) {
    const float* X     = (const float*)d_in[0];
    const float* WQ    = (const float*)d_in[1];
    const float* WK    = (const float*)d_in[2];
    const float* WV    = (const float*)d_in[3];
    const float* WO    = (const float*)d_in[4];
    const float* gamma = (const float*)d_in[5];
    const float* beta  = (const float*)d_in[6];
    const float* W1    = (const float*)d_in[7];
    const float* b1    = (const float*)d_in[8];
    const float* W2    = (const float*)d_in[9];
    const float* b2    = (const float*)d_in[10];
    float* out = (float*)d_out;

    char* ws = (char*)d_ws;
    const size_t MB = 1024 * 1024;
    u16* Qbf   = (u16*)(ws + 0);          // 16 MB [B*S][H*D]
    u16* Kbf   = (u16*)(ws + 16 * MB);    // 16 MB
    u16* Vt    = (u16*)(ws + 32 * MB);    // 16 MB [H*D][B*S]
    u16* vecbf = (u16*)(ws + 48 * MB);    // 16 MB att_vec bf16
    u16* hid   = (u16*)(ws + 0);          // 64 MB, overlays Q/K/Vt/vec (dead by FFN1)
    u16* Xbf   = (u16*)(ws + 64 * MB);    // 16 MB
    u16* WQT   = (u16*)(ws + 80 * MB);    // 2 MB  [H][D][E]
    u16* WKT   = (u16*)(ws + 82 * MB);
    u16* WVT   = (u16*)(ws + 84 * MB);
    u16* WOT   = (u16*)(ws + 86 * MB);    // 2 MB  [E][H*D]
    u16* W1T   = (u16*)(ws + 88 * MB);    // 8 MB  [F][E]
    u16* W2T   = (u16*)(ws + 96 * MB);    // 8 MB  [E][F]
    float* Ms  = (float*)(ws + 104 * MB); // 512 KB
    float* Ls  = (float*)(ws + 104 * MB + 512 * 1024);
    float* vatt  = (float*)(ws + 105 * MB); // 32 MB fp32 (pre-LN1)
    u16*   ln1bf = (u16*)(ws + 137 * MB);   // 16 MB LN1 output (FFN in + resid)

    const int NT = BB * SS;   // 8192 tokens

    // --- one-time converts / weight transposes (bf16, k-innermost) ---
    cvt_bf<<<8192, 256, 0, stream>>>(X, Xbf, NT * EE / 4);
    transp_bf<<<dim3(16, 1, 16), 256, 0, stream>>>(WQ, WQT, EE, DD);
    transp_bf<<<dim3(16, 1, 16), 256, 0, stream>>>(WK, WKT, EE, DD);
    transp_bf<<<dim3(16, 1, 16), 256, 0, stream>>>(WV, WVT, EE, DD);
    transp_bf<<<dim3(16, 16, 1), 256, 0, stream>>>(WO, WOT, HH * DD, EE);
    transp_bf<<<dim3(16, 64, 1), 256, 0, stream>>>(W1, W1T, EE, FF);
    transp_bf<<<dim3(64, 16, 1), 256, 0, stream>>>(W2, W2T, FF, EE);

    // --- projections (Q,K normal layout; V produced transposed) ---
    gemm_bf16<0><<<dim3(64, 8), 256, 0, stream>>>(Xbf, WQT, EE, 1024, Qbf, nullptr, nullptr);
    gemm_bf16<0><<<dim3(64, 8), 256, 0, stream>>>(Xbf, WKT, EE, 1024, Kbf, nullptr, nullptr);
    gemm_bf16<0><<<dim3(8, 64), 256, 0, stream>>>(WVT, Xbf, EE, 8192, Vt, nullptr, nullptr);

    // --- attention (column softmax then /8) ---
    stats_mfma<<<dim3(SS / 128, BB * HH), 256, 0, stream>>>(Qbf, Kbf, Ms, Ls);
    pv_mfma<<<dim3(SS / 128, BB * HH), 256, 0, stream>>>(Qbf, Kbf, Vt, Ms, Ls, vecbf);

    // --- WO + residual X -> vatt (fp32), LN1 -> ln1bf ---
    gemm_bf16<1><<<dim3(64, 8), 256, 0, stream>>>(vecbf, WOT, EE, 1024, vatt, nullptr, X);
    ln_bf_kernel<<<NT, 256, 0, stream>>>(vatt, gamma, beta, ln1bf);

    // --- FFN ---
    gemm_bf16<2><<<dim3(64, 32), 256, 0, stream>>>(ln1bf, W1T, EE, FF, hid, b1, nullptr);
    gemm_bf16<3><<<dim3(64, 8), 256, 0, stream>>>(hid, W2T, FF, 1024, out, b2, ln1bf);

    // --- final LN in place on d_out ---
    ln_kernel<<<NT, 256, 0, stream>>>(out, gamma, beta);
}

// Round 5
// 756.152 us; speedup vs baseline: 1.1260x; 1.1260x over previous
//
#include <hip/hip_runtime.h>
#include <cstddef>
#include <cstdint>

#define BB 4
#define SS 2048
#define EE 1024
#define HH 16
#define DD 64
#define FF 4096

typedef unsigned short u16;
typedef __attribute__((ext_vector_type(8))) short short8;   // 8 bf16 = 4 VGPR (MFMA A/B frag)
typedef __attribute__((ext_vector_type(4))) short short4v;
typedef __attribute__((ext_vector_type(4))) float f32x4;    // MFMA C/D frag

__device__ __forceinline__ u16 f2bf(float x) {
    unsigned u = __builtin_bit_cast(unsigned, x);
    u += 0x7fffu + ((u >> 16) & 1u);   // round-to-nearest-even
    return (u16)(u >> 16);
}
__device__ __forceinline__ float bf2f(u16 h) {
    unsigned u = ((unsigned)h) << 16;
    return __builtin_bit_cast(float, u);
}

// ---------------------------------------------------------------------------
// fp32 -> bf16 elementwise convert (4 elems/thread)
// ---------------------------------------------------------------------------
__global__ __launch_bounds__(256) void cvt_bf(const float* __restrict__ in,
                                              u16* __restrict__ out, int n4) {
    const int i = blockIdx.x * 256 + threadIdx.x;
    if (i < n4) {
        float4 v = reinterpret_cast<const float4*>(in)[i];
        short4v o;
        o.x = (short)f2bf(v.x); o.y = (short)f2bf(v.y);
        o.z = (short)f2bf(v.z); o.w = (short)f2bf(v.w);
        reinterpret_cast<short4v*>(out)[i] = o;
    }
}

// ---------------------------------------------------------------------------
// Transpose + convert: out[c][r] = (bf16) in[r][c].  in: [R][C] fp32, batched.
// grid (R/64, C/64, batch)
// ---------------------------------------------------------------------------
__global__ __launch_bounds__(256) void transp_bf(const float* __restrict__ in,
                                                 u16* __restrict__ out, int R, int C) {
    __shared__ float T[64][65];
    const int r0 = blockIdx.x * 64, c0 = blockIdx.y * 64;
    const size_t zoff = (size_t)blockIdx.z * R * C;
    in += zoff; out += zoff;
    const int tid = threadIdx.x;
#pragma unroll 4
    for (int i = 0; i < 16; ++i) {
        int l = tid + i * 256;
        T[l >> 6][l & 63] = in[(size_t)(r0 + (l >> 6)) * C + c0 + (l & 63)];
    }
    __syncthreads();
#pragma unroll 4
    for (int i = 0; i < 16; ++i) {
        int l = tid + i * 256;
        out[(size_t)(c0 + (l >> 6)) * R + r0 + (l & 63)] = f2bf(T[l & 63][l >> 6]);
    }
}

// ---------------------------------------------------------------------------
// bf16 MFMA GEMM (R2 known-good): 128x128 tile, BK=32, 4 waves, explicit
// VGPR staging with cross-iteration prefetch.
// A [M][K] bf16 row-major (k inner); BT [N][K] bf16 (k inner). C row-major ldc=N.
// EPI: 0 = bf16 out | 1 = f32 out + f32 resid | 2 = bf16 out + bias + relu
//      3 = f32 out + bias + bf16 resid
// ---------------------------------------------------------------------------
template <int EPI>
__global__ __launch_bounds__(256) void gemm_bf16(const u16* __restrict__ A,
                                                 const u16* __restrict__ BT,
                                                 int K, int N,
                                                 void* __restrict__ Cout,
                                                 const float* __restrict__ bias,
                                                 const void* __restrict__ resid) {
    __shared__ u16 As[128 * 40];   // +8 pad
    __shared__ u16 Bs[128 * 40];
    const int tid = threadIdx.x;
    const int w = tid >> 6, l = tid & 63;
    const int quad = l >> 4, lane16 = l & 15;
    const int wr = (w >> 1) * 64, wc = (w & 1) * 64;
    const int m0 = blockIdx.x * 128, n0 = blockIdx.y * 128;
    const u16* Ab = A + (size_t)m0 * K;
    const u16* Bb = BT + (size_t)n0 * K;

    const int sr = tid >> 2;              // 0..63
    const int kg = (tid & 3) * 8;         // k offset 0/8/16/24
    const u16* Apt = Ab + (size_t)sr * K + kg;
    const u16* Bpt = Bb + (size_t)sr * K + kg;
    const size_t rstep = (size_t)64 * K;
    u16* AsW0 = &As[sr * 40 + kg];
    u16* AsW1 = &As[(sr + 64) * 40 + kg];
    u16* BsW0 = &Bs[sr * 40 + kg];
    u16* BsW1 = &Bs[(sr + 64) * 40 + kg];

    f32x4 acc[4][4] = {};
    short8 pa0 = *(const short8*)Apt;
    short8 pa1 = *(const short8*)(Apt + rstep);
    short8 pb0 = *(const short8*)Bpt;
    short8 pb1 = *(const short8*)(Bpt + rstep);

    for (int k0 = 0; k0 < K; k0 += 32) {
        __syncthreads();
        *(short8*)AsW0 = pa0; *(short8*)AsW1 = pa1;
        *(short8*)BsW0 = pb0; *(short8*)BsW1 = pb1;
        __syncthreads();
        if (k0 + 32 < K) {
            const u16* ap = Apt + k0 + 32;
            const u16* bp = Bpt + k0 + 32;
            pa0 = *(const short8*)ap; pa1 = *(const short8*)(ap + rstep);
            pb0 = *(const short8*)bp; pb1 = *(const short8*)(bp + rstep);
        }
        short8 af[4], bf[4];
#pragma unroll
        for (int mf = 0; mf < 4; ++mf)
            af[mf] = *(const short8*)&As[(wr + mf * 16 + lane16) * 40 + quad * 8];
#pragma unroll
        for (int nf = 0; nf < 4; ++nf)
            bf[nf] = *(const short8*)&Bs[(wc + nf * 16 + lane16) * 40 + quad * 8];
#pragma unroll
        for (int mf = 0; mf < 4; ++mf)
#pragma unroll
            for (int nf = 0; nf < 4; ++nf)
                acc[mf][nf] = __builtin_amdgcn_mfma_f32_16x16x32_bf16(af[mf], bf[nf], acc[mf][nf], 0, 0, 0);
    }

#pragma unroll
    for (int mf = 0; mf < 4; ++mf) {
        const int row = m0 + wr + mf * 16 + quad * 4;
#pragma unroll
        for (int nf = 0; nf < 4; ++nf) {
            const int col = n0 + wc + nf * 16 + lane16;
#pragma unroll
            for (int r = 0; r < 4; ++r) {
                float v = acc[mf][nf][r];
                const size_t idx = (size_t)(row + r) * N + col;
                if (EPI == 0) {
                    ((u16*)Cout)[idx] = f2bf(v);
                } else if (EPI == 1) {
                    ((float*)Cout)[idx] = v + ((const float*)resid)[idx];
                } else if (EPI == 2) {
                    v += bias[col];
                    ((u16*)Cout)[idx] = f2bf(fmaxf(v, 0.f));
                } else {
                    v += bias[col] + bf2f(((const u16*)resid)[idx]);
                    ((float*)Cout)[idx] = v;
                }
            }
        }
    }
}

// ---------------------------------------------------------------------------
// Tier A/B pass 1: S^T = K @ Q^T per (bh); P_u[s][t] = bf16(exp(S)) stored to
// global (t-inner, via LDS bounce); l_t = sum_s exp accumulated.
// grid (SS/64 t-tiles, chunk bh)
// ---------------------------------------------------------------------------
__global__ __launch_bounds__(256) void stats_p(const u16* __restrict__ Qg,
                                               const u16* __restrict__ Kg,
                                               u16* __restrict__ P,      // [chunk][SS][SS]
                                               float* __restrict__ Ls,   // [64][SS]
                                               int bh0) {
    __shared__ u16 Qs[128 * 72];
    __shared__ u16 Ps[128 * 72];
    const int tblk = blockIdx.x * 64;
    const int bhr = blockIdx.y;
    const int bh = bh0 + bhr;
    const int b = bh >> 4, h = bh & 15;
    const int tid = threadIdx.x;
    const int w = tid >> 6, l = tid & 63;
    const int quad = l >> 4, lane16 = l & 15;
    const u16* Qp = Qg + (size_t)b * SS * 1024 + h * 64;
    const u16* Kp = Kg + (size_t)b * SS * 1024 + h * 64;
    u16* Pb = P + (size_t)bhr * SS * SS + tblk;

    // K A-frags in registers (loop-invariant): m=t, k=d
    short8 kf[4][2];
#pragma unroll
    for (int mf = 0; mf < 4; ++mf)
#pragma unroll
        for (int ks = 0; ks < 2; ++ks)
            kf[mf][ks] = *(const short8*)(Kp +
                (size_t)(tblk + mf * 16 + lane16) * 1024 + ks * 32 + quad * 8);

    float lacc[4][4] = {};   // [mf][r] partial l sums (t per slot)

    const int qr = tid >> 1;            // 0..127
    const int qc = (tid & 1) * 4;       // chunk base (8-elem chunks)
    const int pr = tid >> 3;            // 0..31 (store phase)
    const int pc = tid & 7;

    for (int it = 0; it < 16; ++it) {
        const int sblk = it * 128;
        __syncthreads();
        {
            const u16* qsrc = Qp + (size_t)(sblk + qr) * 1024;
#pragma unroll
            for (int i = 0; i < 4; ++i)
                *(short8*)&Qs[qr * 72 + (qc + i) * 8] = *(const short8*)(qsrc + (qc + i) * 8);
        }
        __syncthreads();
        f32x4 sc[4][2] = {};
#pragma unroll
        for (int ks = 0; ks < 2; ++ks) {
            short8 bf0 = *(const short8*)&Qs[(w * 32 + lane16) * 72 + ks * 32 + quad * 8];
            short8 bf1 = *(const short8*)&Qs[(w * 32 + 16 + lane16) * 72 + ks * 32 + quad * 8];
#pragma unroll
            for (int mf = 0; mf < 4; ++mf) {
                sc[mf][0] = __builtin_amdgcn_mfma_f32_16x16x32_bf16(kf[mf][ks], bf0, sc[mf][0], 0, 0, 0);
                sc[mf][1] = __builtin_amdgcn_mfma_f32_16x16x32_bf16(kf[mf][ks], bf1, sc[mf][1], 0, 0, 0);
            }
        }
#pragma unroll
        for (int mf = 0; mf < 4; ++mf)
#pragma unroll
            for (int nf = 0; nf < 2; ++nf) {
                const int srow = w * 32 + nf * 16 + lane16;
                float e0 = __expf(sc[mf][nf][0]);
                float e1 = __expf(sc[mf][nf][1]);
                float e2 = __expf(sc[mf][nf][2]);
                float e3 = __expf(sc[mf][nf][3]);
                lacc[mf][0] += e0; lacc[mf][1] += e1;
                lacc[mf][2] += e2; lacc[mf][3] += e3;
                short4v pk;
                pk.x = (short)f2bf(e0); pk.y = (short)f2bf(e1);
                pk.z = (short)f2bf(e2); pk.w = (short)f2bf(e3);
                *(short4v*)&Ps[srow * 72 + mf * 16 + quad * 4] = pk;
            }
        __syncthreads();   // Ps tile complete
#pragma unroll
        for (int i = 0; i < 4; ++i) {
            const int row = pr + i * 32;
            *(short8*)(Pb + (size_t)(sblk + row) * SS + pc * 8) =
                *(const short8*)&Ps[row * 72 + pc * 8];
        }
    }
    // reduce l over the 16 s-lanes (lane16 bits) of each quad
#pragma unroll
    for (int mf = 0; mf < 4; ++mf)
#pragma unroll
        for (int r = 0; r < 4; ++r) {
            float v = lacc[mf][r];
            v += __shfl_xor(v, 1); v += __shfl_xor(v, 2);
            v += __shfl_xor(v, 4); v += __shfl_xor(v, 8);
            lacc[mf][r] = v;
        }
    __syncthreads();
    float* red = (float*)Ps;   // [4 waves][64 t]
    if (lane16 == 0) {
#pragma unroll
        for (int mf = 0; mf < 4; ++mf)
#pragma unroll
            for (int r = 0; r < 4; ++r)
                red[w * 64 + mf * 16 + quad * 4 + r] = lacc[mf][r];
    }
    __syncthreads();
    if (tid < 64)
        Ls[(size_t)bh * SS + tblk + tid] =
            red[tid] + red[64 + tid] + red[128 + tid] + red[192 + tid];
}

// ---------------------------------------------------------------------------
// Scale V rows: Vt[r][b*SS+t] *= 0.125 / l_{b,h(r),t}.  grid (1024, nbatch)
// ---------------------------------------------------------------------------
__global__ __launch_bounds__(256) void vscale(u16* __restrict__ Vtg,
                                              const float* __restrict__ Ls,
                                              int b0) {
    const int r = blockIdx.x;
    const int b = b0 + blockIdx.y;
    const int h = r >> 6;
    const int t0 = threadIdx.x * 8;
    u16* vp = Vtg + (size_t)r * 8192 + b * SS + t0;
    const float* lp = Ls + (size_t)(b * 16 + h) * SS + t0;
    short8 v = *(short8*)vp;
    short8 o;
#pragma unroll
    for (int i = 0; i < 8; ++i)
        o[i] = (short)f2bf(bf2f((u16)v[i]) * (0.125f / lp[i]));
    *(short8*)vp = o;
}

// ---------------------------------------------------------------------------
// Tier A/B pass 2: plain GEMM out = P_u @ Vtilde. 128 s x 64 d per block,
// K = 2048 (t). grid (SS/128, chunk bh)
// ---------------------------------------------------------------------------
__global__ __launch_bounds__(256) void pv_gemm(const u16* __restrict__ P,
                                               const u16* __restrict__ Vtg,
                                               u16* __restrict__ vecbf,
                                               int bh0) {
    __shared__ u16 As[128 * 72];
    __shared__ u16 Bs[64 * 72];
    const int s0 = blockIdx.x * 128;
    const int bhr = blockIdx.y;
    const int bh = bh0 + bhr;
    const int b = bh >> 4, h = bh & 15;
    const int tid = threadIdx.x;
    const int w = tid >> 6, l = tid & 63;
    const int quad = l >> 4, lane16 = l & 15;
    const u16* Ab = P + (size_t)bhr * SS * SS + (size_t)s0 * SS;
    const u16* Bb = Vtg + (size_t)h * 64 * 8192 + (size_t)b * SS;

    const int ar = tid >> 1;          // 0..127
    const int ac = (tid & 1) * 4;     // 4 chunks of 8 elems
    const int br = tid >> 2;          // 0..63
    const int bc = (tid & 3) * 2;     // 2 chunks

    short8 pa[4], pb[2];
#pragma unroll
    for (int i = 0; i < 4; ++i)
        pa[i] = *(const short8*)(Ab + (size_t)ar * SS + (ac + i) * 8);
#pragma unroll
    for (int i = 0; i < 2; ++i)
        pb[i] = *(const short8*)(Bb + (size_t)br * 8192 + (bc + i) * 8);

    f32x4 acc[2][4] = {};
    for (int k0 = 0; k0 < SS; k0 += 64) {
        __syncthreads();
#pragma unroll
        for (int i = 0; i < 4; ++i) *(short8*)&As[ar * 72 + (ac + i) * 8] = pa[i];
#pragma unroll
        for (int i = 0; i < 2; ++i) *(short8*)&Bs[br * 72 + (bc + i) * 8] = pb[i];
        __syncthreads();
        if (k0 + 64 < SS) {
#pragma unroll
            for (int i = 0; i < 4; ++i)
                pa[i] = *(const short8*)(Ab + (size_t)ar * SS + k0 + 64 + (ac + i) * 8);
#pragma unroll
            for (int i = 0; i < 2; ++i)
                pb[i] = *(const short8*)(Bb + (size_t)br * 8192 + k0 + 64 + (bc + i) * 8);
        }
#pragma unroll
        for (int ks = 0; ks < 2; ++ks) {
            short8 af[2], bf[4];
#pragma unroll
            for (int mf = 0; mf < 2; ++mf)
                af[mf] = *(const short8*)&As[(w * 32 + mf * 16 + lane16) * 72 + ks * 32 + quad * 8];
#pragma unroll
            for (int nf = 0; nf < 4; ++nf)
                bf[nf] = *(const short8*)&Bs[(nf * 16 + lane16) * 72 + ks * 32 + quad * 8];
#pragma unroll
            for (int mf = 0; mf < 2; ++mf)
#pragma unroll
                for (int nf = 0; nf < 4; ++nf)
                    acc[mf][nf] = __builtin_amdgcn_mfma_f32_16x16x32_bf16(af[mf], bf[nf], acc[mf][nf], 0, 0, 0);
        }
    }
#pragma unroll
    for (int mf = 0; mf < 2; ++mf)
#pragma unroll
        for (int nf = 0; nf < 4; ++nf) {
            const int col = h * 64 + nf * 16 + lane16;
#pragma unroll
            for (int r = 0; r < 4; ++r) {
                const int srow = s0 + w * 32 + mf * 16 + quad * 4 + r;
                vecbf[(size_t)(b * SS + srow) * 1024 + col] = f2bf(acc[mf][nf][r]);
            }
        }
}

// ---------------------------------------------------------------------------
// Tier C pass 1: l_t = sum_s exp(score). K B-frags in regs; Q staged in LDS.
// grid (SS/128 t-tiles, 64 bh)
// ---------------------------------------------------------------------------
__global__ __launch_bounds__(256) void stats_l(const u16* __restrict__ Qg,
                                               const u16* __restrict__ Kg,
                                               float* __restrict__ Ls) {
    __shared__ u16 Qt[64 * 72];
    const int t0 = blockIdx.x * 128;
    const int bh = blockIdx.y;
    const int b = bh >> 4, h = bh & 15;
    const int tid = threadIdx.x;
    const int w = tid >> 6, l = tid & 63;
    const int quad = l >> 4, lane16 = l & 15;
    const u16* Qp = Qg + (size_t)b * SS * 1024 + h * 64;
    const u16* Kp = Kg + (size_t)b * SS * 1024 + h * 64;
    const int sr = tid >> 3;
    const int dg = (tid & 7) * 8;

    short8 kf[2][2];
#pragma unroll
    for (int nf = 0; nf < 2; ++nf)
#pragma unroll
        for (int ks = 0; ks < 2; ++ks)
            kf[nf][ks] = *(const short8*)(Kp +
                (size_t)(t0 + w * 32 + nf * 16 + lane16) * 1024 + ks * 32 + quad * 8);

    float lcol[2] = {0.f, 0.f};
    for (int st = 0; st < 32; ++st) {
        __syncthreads();
        const u16* qsrc = Qp + (size_t)(st * 64 + sr) * 1024 + dg;
        *(short8*)&Qt[sr * 72 + dg] = *(const short8*)qsrc;
        *(short8*)&Qt[(sr + 32) * 72 + dg] = *(const short8*)(qsrc + (size_t)32 * 1024);
        __syncthreads();
        f32x4 sc[4][2] = {};
#pragma unroll
        for (int ks = 0; ks < 2; ++ks) {
#pragma unroll
            for (int mf = 0; mf < 4; ++mf) {
                short8 afr = *(const short8*)&Qt[(mf * 16 + lane16) * 72 + ks * 32 + quad * 8];
#pragma unroll
                for (int nf = 0; nf < 2; ++nf)
                    sc[mf][nf] = __builtin_amdgcn_mfma_f32_16x16x32_bf16(afr, kf[nf][ks], sc[mf][nf], 0, 0, 0);
            }
        }
#pragma unroll
        for (int nf = 0; nf < 2; ++nf)
#pragma unroll
            for (int mf = 0; mf < 4; ++mf)
#pragma unroll
                for (int r = 0; r < 4; ++r) lcol[nf] += __expf(sc[mf][nf][r]);
    }
#pragma unroll
    for (int nf = 0; nf < 2; ++nf) {
        lcol[nf] += __shfl_xor(lcol[nf], 32);
        lcol[nf] += __shfl_xor(lcol[nf], 16);
        if (quad == 0)
            Ls[(size_t)bh * SS + t0 + w * 32 + nf * 16 + lane16] = lcol[nf];
    }
}

// ---------------------------------------------------------------------------
// Tier C pass 2: S^T = K @ Q^T (Q B-frags in regs); P = bf16(exp(S)) packed
// b64 into Ps[s][t] (stride 72: 16B-aligned rows, 2-way bank alias = free);
// O = P @ Vtilde. Output -> att_vec [B,S,H*D] bf16. grid (SS/128, 64)
// ---------------------------------------------------------------------------
__global__ __launch_bounds__(256) void pv_fused(const u16* __restrict__ Qg,
                                                const u16* __restrict__ Kg,
                                                const u16* __restrict__ Vtg,
                                                u16* __restrict__ vecbf) {
    __shared__ u16 Ks[64 * 72];   // [t][d]
    __shared__ u16 Vs[64 * 72];   // [d][t]
    __shared__ u16 Ps[128 * 72];  // [s][t]
    const int s0 = blockIdx.x * 128;
    const int bh = blockIdx.y;
    const int b = bh >> 4, h = bh & 15;
    const int tid = threadIdx.x;
    const int w = tid >> 6, l = tid & 63;
    const int quad = l >> 4, lane16 = l & 15;
    const u16* Qp = Qg + (size_t)b * SS * 1024 + h * 64;
    const u16* Kp = Kg + (size_t)b * SS * 1024 + h * 64;
    const u16* Vp = Vtg + (size_t)h * 64 * 8192 + (size_t)b * SS;
    const int sr = tid >> 3, dg = (tid & 7) * 8;

    // Q B-frags in registers (loop-invariant)
    short8 qf[2][2];
#pragma unroll
    for (int nf = 0; nf < 2; ++nf)
#pragma unroll
        for (int ks = 0; ks < 2; ++ks)
            qf[nf][ks] = *(const short8*)(Qp +
                (size_t)(s0 + w * 32 + nf * 16 + lane16) * 1024 + ks * 32 + quad * 8);

    f32x4 acc[2][4] = {};
    for (int tt = 0; tt < 32; ++tt) {
        const int t0 = tt * 64;
        __syncthreads();   // all waves done reading Ks/Vs of prev iter
        *(short8*)&Ks[sr * 72 + dg] = *(const short8*)(Kp + (size_t)(t0 + sr) * 1024 + dg);
        *(short8*)&Ks[(sr + 32) * 72 + dg] = *(const short8*)(Kp + (size_t)(t0 + sr + 32) * 1024 + dg);
        *(short8*)&Vs[sr * 72 + dg] = *(const short8*)(Vp + (size_t)sr * 8192 + t0 + dg);
        *(short8*)&Vs[(sr + 32) * 72 + dg] = *(const short8*)(Vp + (size_t)(sr + 32) * 8192 + t0 + dg);
        __syncthreads();
        // S^T = K-tile (A, m=t) @ Q^T (B regs, n=s: wave's 32 rows)
        f32x4 sc[4][2] = {};
#pragma unroll
        for (int ks = 0; ks < 2; ++ks) {
#pragma unroll
            for (int mf = 0; mf < 4; ++mf) {
                short8 afr = *(const short8*)&Ks[(mf * 16 + lane16) * 72 + ks * 32 + quad * 8];
#pragma unroll
                for (int nf = 0; nf < 2; ++nf)
                    sc[mf][nf] = __builtin_amdgcn_mfma_f32_16x16x32_bf16(afr, qf[nf][ks], sc[mf][nf], 0, 0, 0);
            }
        }
        // P = exp(S): 4 consecutive t per C-frag -> one packed b64 store
#pragma unroll
        for (int mf = 0; mf < 4; ++mf)
#pragma unroll
            for (int nf = 0; nf < 2; ++nf) {
                const int srow = w * 32 + nf * 16 + lane16;
                short4v pk;
                pk.x = (short)f2bf(__expf(sc[mf][nf][0]));
                pk.y = (short)f2bf(__expf(sc[mf][nf][1]));
                pk.z = (short)f2bf(__expf(sc[mf][nf][2]));
                pk.w = (short)f2bf(__expf(sc[mf][nf][3]));
                *(short4v*)&Ps[srow * 72 + mf * 16 + quad * 4] = pk;
            }
        // PV: Ps rows [w*32, w*32+32) are wave-local -> no barrier
#pragma unroll
        for (int ks = 0; ks < 2; ++ks) {
            short8 bfr[4];
#pragma unroll
            for (int nf = 0; nf < 4; ++nf)
                bfr[nf] = *(const short8*)&Vs[(nf * 16 + lane16) * 72 + ks * 32 + quad * 8];
            short8 afr[2];
#pragma unroll
            for (int mf = 0; mf < 2; ++mf)
                afr[mf] = *(const short8*)&Ps[(w * 32 + mf * 16 + lane16) * 72 + ks * 32 + quad * 8];
#pragma unroll
            for (int mf = 0; mf < 2; ++mf)
#pragma unroll
                for (int nf = 0; nf < 4; ++nf)
                    acc[mf][nf] = __builtin_amdgcn_mfma_f32_16x16x32_bf16(afr[mf], bfr[nf], acc[mf][nf], 0, 0, 0);
        }
    }
#pragma unroll
    for (int mf = 0; mf < 2; ++mf)
#pragma unroll
        for (int nf = 0; nf < 4; ++nf) {
            const int col = h * 64 + nf * 16 + lane16;
#pragma unroll
            for (int r = 0; r < 4; ++r) {
                const int srow = s0 + w * 32 + mf * 16 + quad * 4 + r;
                vecbf[(size_t)(b * SS + srow) * 1024 + col] = f2bf(acc[mf][nf][r]);
            }
        }
}

// ---------------------------------------------------------------------------
// LayerNorm over last dim (E=1024), fp32 in -> bf16 out
// ---------------------------------------------------------------------------
__global__ __launch_bounds__(256) void ln_bf_kernel(const float* __restrict__ buf,
                                                    const float* __restrict__ g,
                                                    const float* __restrict__ be,
                                                    u16* __restrict__ outbf) {
    const int row = blockIdx.x;
    const int tid = threadIdx.x;
    const float* p = buf + (size_t)row * EE;
    float4 x = reinterpret_cast<const float4*>(p)[tid];
    float s = x.x + x.y + x.z + x.w;
    __shared__ float red[4];
#pragma unroll
    for (int o = 32; o > 0; o >>= 1) s += __shfl_down(s, o);
    const int wid = tid >> 6, lane = tid & 63;
    if (lane == 0) red[wid] = s;
    __syncthreads();
    const float mu = (red[0] + red[1] + red[2] + red[3]) * (1.0f / EE);
    __syncthreads();
    const float dx = x.x - mu, dy = x.y - mu, dz = x.z - mu, dw = x.w - mu;
    float v = dx * dx + dy * dy + dz * dz + dw * dw;
#pragma unroll
    for (int o = 32; o > 0; o >>= 1) v += __shfl_down(v, o);
    if (lane == 0) red[wid] = v;
    __syncthreads();
    const float var = (red[0] + red[1] + red[2] + red[3]) * (1.0f / EE);
    const float rs = rsqrtf(var + 1e-5f);
    float4 gv = reinterpret_cast<const float4*>(g)[tid];
    float4 bv = reinterpret_cast<const float4*>(be)[tid];
    short4v o;
    o.x = (short)f2bf(dx * rs * gv.x + bv.x);
    o.y = (short)f2bf(dy * rs * gv.y + bv.y);
    o.z = (short)f2bf(dz * rs * gv.z + bv.z);
    o.w = (short)f2bf(dw * rs * gv.w + bv.w);
    reinterpret_cast<short4v*>(outbf + (size_t)row * EE)[tid] = o;
}

// In-place fp32 LayerNorm (final output)
__global__ __launch_bounds__(256) void ln_kernel(float* __restrict__ buf,
                                                 const float* __restrict__ g,
                                                 const float* __restrict__ be) {
    const int row = blockIdx.x;
    const int tid = threadIdx.x;
    float* p = buf + (size_t)row * EE;
    float4 x = reinterpret_cast<float4*>(p)[tid];
    float s = x.x + x.y + x.z + x.w;
    __shared__ float red[4];
#pragma unroll
    for (int o = 32; o > 0; o >>= 1) s += __shfl_down(s, o);
    const int wid = tid >> 6, lane = tid & 63;
    if (lane == 0) red[wid] = s;
    __syncthreads();
    const float mu = (red[0] + red[1] + red[2] + red[3]) * (1.0f / EE);
    __syncthreads();
    const float dx = x.x - mu, dy = x.y - mu, dz = x.z - mu, dw = x.w - mu;
    float v = dx * dx + dy * dy + dz * dz + dw * dw;
#pragma unroll
    for (int o = 32; o > 0; o >>= 1) v += __shfl_down(v, o);
    if (lane == 0) red[wid] = v;
    __syncthreads();
    const float var = (red[0] + red[1] + red[2] + red[3]) * (1.0f / EE);
    const float rs = rsqrtf(var + 1e-5f);
    float4 gv = reinterpret_cast<const float4*>(g)[tid];
    float4 bv = reinterpret_cast<const float4*>(be)[tid];
    float4 y;
    y.x = dx * rs * gv.x + bv.x;
    y.y = dy * rs * gv.y + bv.y;
    y.z = dz * rs * gv.z + bv.z;
    y.w = dw * rs * gv.w + bv.w;
    reinterpret_cast<float4*>(p)[tid] = y;
}

// ---------------------------------------------------------------------------
extern "C" void kernel_launch(void* const* d_in, const int* in_sizes, int n_in,
                              void* d_out, int out_size, void* d_ws, size_t ws_size,
                              hipStream_t stream) {
    const float* X     = (const float*)d_in[0];
    const float* WQ    = (const float*)d_in[1];
    const float* WK    = (const float*)d_in[2];
    const float* WV    = (const float*)d_in[3];
    const float* WO    = (const float*)d_in[4];
    const float* gamma = (const float*)d_in[5];
    const float* beta  = (const float*)d_in[6];
    const float* W1    = (const float*)d_in[7];
    const float* b1    = (const float*)d_in[8];
    const float* W2    = (const float*)d_in[9];
    const float* b2    = (const float*)d_in[10];
    float* out = (float*)d_out;

    char* ws = (char*)d_ws;
    const size_t MB = 1024 * 1024;
    // Lean layout (fixed part ends at 153 MB; ws >= 153 MB proven by R2/R3):
    u16* WQT   = (u16*)(ws + 0);          // 2 MB [H][D][E]
    u16* WKT   = (u16*)(ws + 2 * MB);
    u16* WVT   = (u16*)(ws + 4 * MB);
    u16* WOT   = (u16*)(ws + 6 * MB);     // 2 MB [E][H*D]
    u16* W1T   = (u16*)(ws + 8 * MB);     // 8 MB [F][E]
    u16* W2T   = (u16*)(ws + 16 * MB);    // 8 MB [E][F]
    float* Ls  = (float*)(ws + 24 * MB);  // 512 KB [64 bh][SS]
    u16* Qbf   = (u16*)(ws + 25 * MB);    // 16 MB [B*S][H*D]
    u16* Kbf   = (u16*)(ws + 41 * MB);    // 16 MB
    u16* Vt    = (u16*)(ws + 57 * MB);    // 16 MB [H*D][B*S]
    u16* vecbf = (u16*)(ws + 73 * MB);    // 16 MB att_vec bf16
    u16* hid   = (u16*)(ws + 25 * MB);    // 64 MB FFN hidden, overlays Q/K/Vt/vec
    u16* Xbf   = (u16*)(ws + 89 * MB);    // 16 MB (dead after projections)
    float* vatt  = (float*)(ws + 105 * MB); // 32 MB fp32 (pre-LN1)
    u16*   ln1bf = (u16*)(ws + 137 * MB);   // 16 MB LN1 out  -> fixed end 153 MB
    u16*   P     = (u16*)(ws + 89 * MB);    // Tier A/B: over dead Xbf onward

    const int NT = BB * SS;   // 8192 tokens
    // Tier select (ws_size constant per session -> same work every call)
    const int chunk = (ws_size >= 345 * MB) ? 32 : (ws_size >= 217 * MB) ? 16 : 0;

    // --- one-time converts / weight transposes (bf16, k-innermost) ---
    cvt_bf<<<8192, 256, 0, stream>>>(X, Xbf, NT * EE / 4);
    transp_bf<<<dim3(16, 1, 16), 256, 0, stream>>>(WQ, WQT, EE, DD);
    transp_bf<<<dim3(16, 1, 16), 256, 0, stream>>>(WK, WKT, EE, DD);
    transp_bf<<<dim3(16, 1, 16), 256, 0, stream>>>(WV, WVT, EE, DD);
    transp_bf<<<dim3(16, 16, 1), 256, 0, stream>>>(WO, WOT, HH * DD, EE);
    transp_bf<<<dim3(16, 64, 1), 256, 0, stream>>>(W1, W1T, EE, FF);
    transp_bf<<<dim3(64, 16, 1), 256, 0, stream>>>(W2, W2T, FF, EE);

    // --- projections (Q,K normal layout; V produced transposed) ---
    gemm_bf16<0><<<dim3(64, 8), 256, 0, stream>>>(Xbf, WQT, EE, 1024, Qbf, nullptr, nullptr);
    gemm_bf16<0><<<dim3(64, 8), 256, 0, stream>>>(Xbf, WKT, EE, 1024, Kbf, nullptr, nullptr);
    gemm_bf16<0><<<dim3(8, 64), 256, 0, stream>>>(WVT, Xbf, EE, 8192, Vt, nullptr, nullptr);

    // --- attention (column softmax then /8) ---
    if (chunk > 0) {
        const int rounds = 64 / chunk;
        const int nb = chunk / 16;   // batches per round
        for (int r = 0; r < rounds; ++r) {
            const int bh0 = chunk * r;
            stats_p<<<dim3(SS / 64, chunk), 256, 0, stream>>>(Qbf, Kbf, P, Ls, bh0);
            vscale<<<dim3(1024, nb), 256, 0, stream>>>(Vt, Ls, bh0 / 16);
            pv_gemm<<<dim3(SS / 128, chunk), 256, 0, stream>>>(P, Vt, vecbf, bh0);
        }
    } else {
        stats_l<<<dim3(SS / 128, BB * HH), 256, 0, stream>>>(Qbf, Kbf, Ls);
        vscale<<<dim3(1024, BB), 256, 0, stream>>>(Vt, Ls, 0);
        pv_fused<<<dim3(SS / 128, BB * HH), 256, 0, stream>>>(Qbf, Kbf, Vt, vecbf);
    }

    // --- WO + residual X -> vatt (fp32), LN1 -> ln1bf ---
    gemm_bf16<1><<<dim3(64, 8), 256, 0, stream>>>(vecbf, WOT, EE, 1024, vatt, nullptr, X);
    ln_bf_kernel<<<NT, 256, 0, stream>>>(vatt, gamma, beta, ln1bf);

    // --- FFN ---
    gemm_bf16<2><<<dim3(64, 32), 256, 0, stream>>>(ln1bf, W1T, EE, FF, hid, b1, nullptr);
    gemm_bf16<3><<<dim3(64, 8), 256, 0, stream>>>(hid, W2T, FF, 1024, out, b2, ln1bf);

    // --- final LN in place on d_out ---
    ln_kernel<<<NT, 256, 0, stream>>>(out, gamma, beta);
}

// Round 6
// 646.014 us; speedup vs baseline: 1.3180x; 1.1705x over previous
//
#include <hip/hip_runtime.h>
#include <cstddef>
#include <cstdint>

#define BB 4
#define SS 2048
#define EE 1024
#define HH 16
#define DD 64
#define FF 4096

typedef unsigned short u16;
typedef __attribute__((ext_vector_type(8))) short short8;   // 8 bf16 = 4 VGPR (MFMA A/B frag)
typedef __attribute__((ext_vector_type(4))) short short4v;
typedef __attribute__((ext_vector_type(4))) float f32x4;    // MFMA C/D frag

__device__ __forceinline__ u16 f2bf(float x) {
    unsigned u = __builtin_bit_cast(unsigned, x);
    u += 0x7fffu + ((u >> 16) & 1u);   // round-to-nearest-even
    return (u16)(u >> 16);
}
__device__ __forceinline__ float bf2f(u16 h) {
    unsigned u = ((unsigned)h) << 16;
    return __builtin_bit_cast(float, u);
}

// async global->LDS DMA, 16B per lane; LDS dest is wave-uniform base + lane*16B
#define GLD_LDS16(g, l)                                                     \
    __builtin_amdgcn_global_load_lds(                                       \
        (const __attribute__((address_space(1))) void*)(g),                 \
        (__attribute__((address_space(3))) void*)(l), 16, 0, 0)

// ---------------------------------------------------------------------------
// fp32 -> bf16 elementwise convert (4 elems/thread)
// ---------------------------------------------------------------------------
__global__ __launch_bounds__(256) void cvt_bf(const float* __restrict__ in,
                                              u16* __restrict__ out, int n4) {
    const int i = blockIdx.x * 256 + threadIdx.x;
    if (i < n4) {
        float4 v = reinterpret_cast<const float4*>(in)[i];
        short4v o;
        o.x = (short)f2bf(v.x); o.y = (short)f2bf(v.y);
        o.z = (short)f2bf(v.z); o.w = (short)f2bf(v.w);
        reinterpret_cast<short4v*>(out)[i] = o;
    }
}

// ---------------------------------------------------------------------------
// Transpose + convert: out[c][r] = (bf16) in[r][c].  in: [R][C] fp32, batched.
// grid (R/64, C/64, batch)
// ---------------------------------------------------------------------------
__global__ __launch_bounds__(256) void transp_bf(const float* __restrict__ in,
                                                 u16* __restrict__ out, int R, int C) {
    __shared__ float T[64][65];
    const int r0 = blockIdx.x * 64, c0 = blockIdx.y * 64;
    const size_t zoff = (size_t)blockIdx.z * R * C;
    in += zoff; out += zoff;
    const int tid = threadIdx.x;
#pragma unroll 4
    for (int i = 0; i < 16; ++i) {
        int l = tid + i * 256;
        T[l >> 6][l & 63] = in[(size_t)(r0 + (l >> 6)) * C + c0 + (l & 63)];
    }
    __syncthreads();
#pragma unroll 4
    for (int i = 0; i < 16; ++i) {
        int l = tid + i * 256;
        out[(size_t)(c0 + (l >> 6)) * R + r0 + (l & 63)] = f2bf(T[l & 63][l >> 6]);
    }
}

// ---------------------------------------------------------------------------
// bf16 MFMA GEMM, m97 pattern: 128x128 tile, BK=32, 4 waves (64x64 quadrant
// each), async global_load_lds staging into unpadded [128][32] LDS tiles.
// A [M][K] bf16 row-major (k inner); BT [N][K] bf16 (k inner). C row-major ldc=N.
// EPI: 0 = bf16 out | 1 = f32 out + f32 resid | 2 = bf16 out + bias + relu
//      3 = f32 out + bias + bf16 resid
// ---------------------------------------------------------------------------
template <int EPI>
__global__ __launch_bounds__(256) void gemm_bf16(const u16* __restrict__ A,
                                                 const u16* __restrict__ BT,
                                                 int K, int N,
                                                 void* __restrict__ Cout,
                                                 const float* __restrict__ bias,
                                                 const void* __restrict__ resid) {
    __shared__ u16 As[128 * 32];
    __shared__ u16 Bs[128 * 32];
    const int tid = threadIdx.x;
    const int w = tid >> 6, l = tid & 63;
    const int quad = l >> 4, lane16 = l & 15;
    const int wr = (w >> 1) * 64, wc = (w & 1) * 64;
    const int m0 = blockIdx.x * 128, n0 = blockIdx.y * 128;
    // DMA: wave w stages rows [w*32, w*32+16) then +16; lane l -> row w*32+(l>>2),
    // k-chunk (l&3)*8. LDS dest = wave base + lane*16B, matching row*64+chunk*16.
    const int drow = w * 32 + (l >> 2);
    const int dk = (l & 3) * 8;
    const u16* Ag = A + (size_t)(m0 + drow) * K + dk;
    const u16* Bg = BT + (size_t)(n0 + drow) * K + dk;
    const size_t r16 = (size_t)16 * K;
    u16* AsD = &As[w * 1024];   // wave-uniform
    u16* BsD = &Bs[w * 1024];

    f32x4 acc[4][4] = {};
    for (int k0 = 0; k0 < K; k0 += 32) {
        __syncthreads();
        GLD_LDS16(Ag + k0, AsD);
        GLD_LDS16(Ag + k0 + r16, AsD + 512);
        GLD_LDS16(Bg + k0, BsD);
        GLD_LDS16(Bg + k0 + r16, BsD + 512);
        __syncthreads();   // drains vmcnt: DMA data visible
        short8 af[4], bf[4];
#pragma unroll
        for (int mf = 0; mf < 4; ++mf)
            af[mf] = *(const short8*)&As[(wr + mf * 16 + lane16) * 32 + quad * 8];
#pragma unroll
        for (int nf = 0; nf < 4; ++nf)
            bf[nf] = *(const short8*)&Bs[(wc + nf * 16 + lane16) * 32 + quad * 8];
#pragma unroll
        for (int mf = 0; mf < 4; ++mf)
#pragma unroll
            for (int nf = 0; nf < 4; ++nf)
                acc[mf][nf] = __builtin_amdgcn_mfma_f32_16x16x32_bf16(af[mf], bf[nf], acc[mf][nf], 0, 0, 0);
    }

#pragma unroll
    for (int mf = 0; mf < 4; ++mf) {
        const int row = m0 + wr + mf * 16 + quad * 4;
#pragma unroll
        for (int nf = 0; nf < 4; ++nf) {
            const int col = n0 + wc + nf * 16 + lane16;
#pragma unroll
            for (int r = 0; r < 4; ++r) {
                float v = acc[mf][nf][r];
                const size_t idx = (size_t)(row + r) * N + col;
                if (EPI == 0) {
                    ((u16*)Cout)[idx] = f2bf(v);
                } else if (EPI == 1) {
                    ((float*)Cout)[idx] = v + ((const float*)resid)[idx];
                } else if (EPI == 2) {
                    v += bias[col];
                    ((u16*)Cout)[idx] = f2bf(fmaxf(v, 0.f));
                } else {
                    v += bias[col] + bf2f(((const u16*)resid)[idx]);
                    ((float*)Cout)[idx] = v;
                }
            }
        }
    }
}

// ---------------------------------------------------------------------------
// Attention pass 1: l_t = sum_s exp(score). K B-frags in regs (loop-invariant);
// Q staged in LDS with cross-iteration VGPR prefetch.
// grid (SS/128 t-tiles, 64 bh)
// ---------------------------------------------------------------------------
__global__ __launch_bounds__(256) void stats_l(const u16* __restrict__ Qg,
                                               const u16* __restrict__ Kg,
                                               float* __restrict__ Ls) {
    __shared__ u16 Qt[64 * 72];
    const int t0 = blockIdx.x * 128;
    const int bh = blockIdx.y;
    const int b = bh >> 4, h = bh & 15;
    const int tid = threadIdx.x;
    const int w = tid >> 6, l = tid & 63;
    const int quad = l >> 4, lane16 = l & 15;
    const u16* Qp = Qg + (size_t)b * SS * 1024 + h * 64;
    const u16* Kp = Kg + (size_t)b * SS * 1024 + h * 64;
    const int sr = tid >> 3;
    const int dg = (tid & 7) * 8;

    short8 kf[2][2];
#pragma unroll
    for (int nf = 0; nf < 2; ++nf)
#pragma unroll
        for (int ks = 0; ks < 2; ++ks)
            kf[nf][ks] = *(const short8*)(Kp +
                (size_t)(t0 + w * 32 + nf * 16 + lane16) * 1024 + ks * 32 + quad * 8);

    const u16* qsrc0 = Qp + (size_t)sr * 1024 + dg;
    short8 pq0 = *(const short8*)qsrc0;
    short8 pq1 = *(const short8*)(qsrc0 + (size_t)32 * 1024);

    float lcol[2] = {0.f, 0.f};
    for (int st = 0; st < 32; ++st) {
        __syncthreads();
        *(short8*)&Qt[sr * 72 + dg] = pq0;
        *(short8*)&Qt[(sr + 32) * 72 + dg] = pq1;
        __syncthreads();
        if (st + 1 < 32) {
            const u16* qsrc = Qp + (size_t)((st + 1) * 64 + sr) * 1024 + dg;
            pq0 = *(const short8*)qsrc;
            pq1 = *(const short8*)(qsrc + (size_t)32 * 1024);
        }
        f32x4 sc[4][2] = {};
#pragma unroll
        for (int ks = 0; ks < 2; ++ks) {
#pragma unroll
            for (int mf = 0; mf < 4; ++mf) {
                short8 afr = *(const short8*)&Qt[(mf * 16 + lane16) * 72 + ks * 32 + quad * 8];
#pragma unroll
                for (int nf = 0; nf < 2; ++nf)
                    sc[mf][nf] = __builtin_amdgcn_mfma_f32_16x16x32_bf16(afr, kf[nf][ks], sc[mf][nf], 0, 0, 0);
            }
        }
#pragma unroll
        for (int nf = 0; nf < 2; ++nf)
#pragma unroll
            for (int mf = 0; mf < 4; ++mf)
#pragma unroll
                for (int r = 0; r < 4; ++r) lcol[nf] += __expf(sc[mf][nf][r]);
    }
#pragma unroll
    for (int nf = 0; nf < 2; ++nf) {
        lcol[nf] += __shfl_xor(lcol[nf], 32);
        lcol[nf] += __shfl_xor(lcol[nf], 16);
        if (quad == 0)
            Ls[(size_t)bh * SS + t0 + w * 32 + nf * 16 + lane16] = lcol[nf];
    }
}

// ---------------------------------------------------------------------------
// Scale V rows: Vt[r][b*SS+t] *= 0.125 / l_{b,h(r),t}.  grid (1024, B)
// ---------------------------------------------------------------------------
__global__ __launch_bounds__(256) void vscale(u16* __restrict__ Vtg,
                                              const float* __restrict__ Ls) {
    const int r = blockIdx.x;
    const int b = blockIdx.y;
    const int h = r >> 6;
    const int t0 = threadIdx.x * 8;
    u16* vp = Vtg + (size_t)r * 8192 + b * SS + t0;
    const float* lp = Ls + (size_t)(b * 16 + h) * SS + t0;
    short8 v = *(short8*)vp;
    short8 o;
#pragma unroll
    for (int i = 0; i < 8; ++i)
        o[i] = (short)f2bf(bf2f((u16)v[i]) * (0.125f / lp[i]));
    *(short8*)vp = o;
}

// ---------------------------------------------------------------------------
// Attention pass 2 (fused): S^T = K @ Q^T (Q B-frags in regs); P = bf16(exp(S))
// packed b64 into Ps[s][t] (stride 72: 16B-aligned, 2-way bank alias = free);
// O = P @ Vtilde. K/V tiles staged via LDS with cross-iteration VGPR prefetch.
// Output -> att_vec [B,S,H*D] bf16. grid (SS/128, 64)
// ---------------------------------------------------------------------------
__global__ __launch_bounds__(256) void pv_fused(const u16* __restrict__ Qg,
                                                const u16* __restrict__ Kg,
                                                const u16* __restrict__ Vtg,
                                                u16* __restrict__ vecbf) {
    __shared__ u16 Ks[64 * 72];   // [t][d]
    __shared__ u16 Vs[64 * 72];   // [d][t]
    __shared__ u16 Ps[128 * 72];  // [s][t]
    const int s0 = blockIdx.x * 128;
    const int bh = blockIdx.y;
    const int b = bh >> 4, h = bh & 15;
    const int tid = threadIdx.x;
    const int w = tid >> 6, l = tid & 63;
    const int quad = l >> 4, lane16 = l & 15;
    const u16* Qp = Qg + (size_t)b * SS * 1024 + h * 64;
    const u16* Kp = Kg + (size_t)b * SS * 1024 + h * 64;
    const u16* Vp = Vtg + (size_t)h * 64 * 8192 + (size_t)b * SS;
    const int sr = tid >> 3, dg = (tid & 7) * 8;

    // Q B-frags in registers (loop-invariant)
    short8 qf[2][2];
#pragma unroll
    for (int nf = 0; nf < 2; ++nf)
#pragma unroll
        for (int ks = 0; ks < 2; ++ks)
            qf[nf][ks] = *(const short8*)(Qp +
                (size_t)(s0 + w * 32 + nf * 16 + lane16) * 1024 + ks * 32 + quad * 8);

    // prefetch first K/V tile
    short8 pk0 = *(const short8*)(Kp + (size_t)sr * 1024 + dg);
    short8 pk1 = *(const short8*)(Kp + (size_t)(sr + 32) * 1024 + dg);
    short8 pv0 = *(const short8*)(Vp + (size_t)sr * 8192 + dg);
    short8 pv1 = *(const short8*)(Vp + (size_t)(sr + 32) * 8192 + dg);

    f32x4 acc[2][4] = {};
    for (int tt = 0; tt < 32; ++tt) {
        __syncthreads();   // all waves done reading Ks/Vs of prev iter
        *(short8*)&Ks[sr * 72 + dg] = pk0;
        *(short8*)&Ks[(sr + 32) * 72 + dg] = pk1;
        *(short8*)&Vs[sr * 72 + dg] = pv0;
        *(short8*)&Vs[(sr + 32) * 72 + dg] = pv1;
        __syncthreads();
        if (tt + 1 < 32) {
            const int t1 = (tt + 1) * 64;
            pk0 = *(const short8*)(Kp + (size_t)(t1 + sr) * 1024 + dg);
            pk1 = *(const short8*)(Kp + (size_t)(t1 + sr + 32) * 1024 + dg);
            pv0 = *(const short8*)(Vp + (size_t)sr * 8192 + t1 + dg);
            pv1 = *(const short8*)(Vp + (size_t)(sr + 32) * 8192 + t1 + dg);
        }
        // S^T = K-tile (A, m=t) @ Q^T (B regs, n=s: wave's 32 rows)
        f32x4 sc[4][2] = {};
#pragma unroll
        for (int ks = 0; ks < 2; ++ks) {
#pragma unroll
            for (int mf = 0; mf < 4; ++mf) {
                short8 afr = *(const short8*)&Ks[(mf * 16 + lane16) * 72 + ks * 32 + quad * 8];
#pragma unroll
                for (int nf = 0; nf < 2; ++nf)
                    sc[mf][nf] = __builtin_amdgcn_mfma_f32_16x16x32_bf16(afr, qf[nf][ks], sc[mf][nf], 0, 0, 0);
            }
        }
        // P = exp(S): 4 consecutive t per C-frag -> one packed b64 store
#pragma unroll
        for (int mf = 0; mf < 4; ++mf)
#pragma unroll
            for (int nf = 0; nf < 2; ++nf) {
                const int srow = w * 32 + nf * 16 + lane16;
                short4v pk;
                pk.x = (short)f2bf(__expf(sc[mf][nf][0]));
                pk.y = (short)f2bf(__expf(sc[mf][nf][1]));
                pk.z = (short)f2bf(__expf(sc[mf][nf][2]));
                pk.w = (short)f2bf(__expf(sc[mf][nf][3]));
                *(short4v*)&Ps[srow * 72 + mf * 16 + quad * 4] = pk;
            }
        // PV: Ps rows [w*32, w*32+32) are wave-local -> no barrier
#pragma unroll
        for (int ks = 0; ks < 2; ++ks) {
            short8 bfr[4];
#pragma unroll
            for (int nf = 0; nf < 4; ++nf)
                bfr[nf] = *(const short8*)&Vs[(nf * 16 + lane16) * 72 + ks * 32 + quad * 8];
            short8 afr[2];
#pragma unroll
            for (int mf = 0; mf < 2; ++mf)
                afr[mf] = *(const short8*)&Ps[(w * 32 + mf * 16 + lane16) * 72 + ks * 32 + quad * 8];
#pragma unroll
            for (int mf = 0; mf < 2; ++mf)
#pragma unroll
                for (int nf = 0; nf < 4; ++nf)
                    acc[mf][nf] = __builtin_amdgcn_mfma_f32_16x16x32_bf16(afr[mf], bfr[nf], acc[mf][nf], 0, 0, 0);
        }
    }
#pragma unroll
    for (int mf = 0; mf < 2; ++mf)
#pragma unroll
        for (int nf = 0; nf < 4; ++nf) {
            const int col = h * 64 + nf * 16 + lane16;
#pragma unroll
            for (int r = 0; r < 4; ++r) {
                const int srow = s0 + w * 32 + mf * 16 + quad * 4 + r;
                vecbf[(size_t)(b * SS + srow) * 1024 + col] = f2bf(acc[mf][nf][r]);
            }
        }
}

// ---------------------------------------------------------------------------
// LayerNorm over last dim (E=1024), fp32 in -> bf16 out
// ---------------------------------------------------------------------------
__global__ __launch_bounds__(256) void ln_bf_kernel(const float* __restrict__ buf,
                                                    const float* __restrict__ g,
                                                    const float* __restrict__ be,
                                                    u16* __restrict__ outbf) {
    const int row = blockIdx.x;
    const int tid = threadIdx.x;
    const float* p = buf + (size_t)row * EE;
    float4 x = reinterpret_cast<const float4*>(p)[tid];
    float s = x.x + x.y + x.z + x.w;
    __shared__ float red[4];
#pragma unroll
    for (int o = 32; o > 0; o >>= 1) s += __shfl_down(s, o);
    const int wid = tid >> 6, lane = tid & 63;
    if (lane == 0) red[wid] = s;
    __syncthreads();
    const float mu = (red[0] + red[1] + red[2] + red[3]) * (1.0f / EE);
    __syncthreads();
    const float dx = x.x - mu, dy = x.y - mu, dz = x.z - mu, dw = x.w - mu;
    float v = dx * dx + dy * dy + dz * dz + dw * dw;
#pragma unroll
    for (int o = 32; o > 0; o >>= 1) v += __shfl_down(v, o);
    if (lane == 0) red[wid] = v;
    __syncthreads();
    const float var = (red[0] + red[1] + red[2] + red[3]) * (1.0f / EE);
    const float rs = rsqrtf(var + 1e-5f);
    float4 gv = reinterpret_cast<const float4*>(g)[tid];
    float4 bv = reinterpret_cast<const float4*>(be)[tid];
    short4v o;
    o.x = (short)f2bf(dx * rs * gv.x + bv.x);
    o.y = (short)f2bf(dy * rs * gv.y + bv.y);
    o.z = (short)f2bf(dz * rs * gv.z + bv.z);
    o.w = (short)f2bf(dw * rs * gv.w + bv.w);
    reinterpret_cast<short4v*>(outbf + (size_t)row * EE)[tid] = o;
}

// In-place fp32 LayerNorm (final output)
__global__ __launch_bounds__(256) void ln_kernel(float* __restrict__ buf,
                                                 const float* __restrict__ g,
                                                 const float* __restrict__ be) {
    const int row = blockIdx.x;
    const int tid = threadIdx.x;
    float* p = buf + (size_t)row * EE;
    float4 x = reinterpret_cast<float4*>(p)[tid];
    float s = x.x + x.y + x.z + x.w;
    __shared__ float red[4];
#pragma unroll
    for (int o = 32; o > 0; o >>= 1) s += __shfl_down(s, o);
    const int wid = tid >> 6, lane = tid & 63;
    if (lane == 0) red[wid] = s;
    __syncthreads();
    const float mu = (red[0] + red[1] + red[2] + red[3]) * (1.0f / EE);
    __syncthreads();
    const float dx = x.x - mu, dy = x.y - mu, dz = x.z - mu, dw = x.w - mu;
    float v = dx * dx + dy * dy + dz * dz + dw * dw;
#pragma unroll
    for (int o = 32; o > 0; o >>= 1) v += __shfl_down(v, o);
    if (lane == 0) red[wid] = v;
    __syncthreads();
    const float var = (red[0] + red[1] + red[2] + red[3]) * (1.0f / EE);
    const float rs = rsqrtf(var + 1e-5f);
    float4 gv = reinterpret_cast<const float4*>(g)[tid];
    float4 bv = reinterpret_cast<const float4*>(be)[tid];
    float4 y;
    y.x = dx * rs * gv.x + bv.x;
    y.y = dy * rs * gv.y + bv.y;
    y.z = dz * rs * gv.z + bv.z;
    y.w = dw * rs * gv.w + bv.w;
    reinterpret_cast<float4*>(p)[tid] = y;
}

// ---------------------------------------------------------------------------
extern "C" void kernel_launch(void* const* d_in, const int* in_sizes, int n_in,
                              void* d_out, int out_size, void* d_ws, size_t ws_size,
                              hipStream_t stream) {
    const float* X     = (const float*)d_in[0];
    const float* WQ    = (const float*)d_in[1];
    const float* WK    = (const float*)d_in[2];
    const float* WV    = (const float*)d_in[3];
    const float* WO    = (const float*)d_in[4];
    const float* gamma = (const float*)d_in[5];
    const float* beta  = (const float*)d_in[6];
    const float* W1    = (const float*)d_in[7];
    const float* b1    = (const float*)d_in[8];
    const float* W2    = (const float*)d_in[9];
    const float* b2    = (const float*)d_in[10];
    float* out = (float*)d_out;

    char* ws = (char*)d_ws;
    const size_t MB = 1024 * 1024;
    // Lean layout, fixed end 153 MB (<= proven ws)
    u16* WQT   = (u16*)(ws + 0);          // 2 MB [H][D][E]
    u16* WKT   = (u16*)(ws + 2 * MB);
    u16* WVT   = (u16*)(ws + 4 * MB);
    u16* WOT   = (u16*)(ws + 6 * MB);     // 2 MB [E][H*D]
    u16* W1T   = (u16*)(ws + 8 * MB);     // 8 MB [F][E]
    u16* W2T   = (u16*)(ws + 16 * MB);    // 8 MB [E][F]
    float* Ls  = (float*)(ws + 24 * MB);  // 512 KB [64 bh][SS]
    u16* Qbf   = (u16*)(ws + 25 * MB);    // 16 MB [B*S][H*D]
    u16* Kbf   = (u16*)(ws + 41 * MB);    // 16 MB
    u16* Vt    = (u16*)(ws + 57 * MB);    // 16 MB [H*D][B*S]
    u16* vecbf = (u16*)(ws + 73 * MB);    // 16 MB att_vec bf16
    u16* hid   = (u16*)(ws + 25 * MB);    // 64 MB FFN hidden, overlays Q/K/Vt/vec
    u16* Xbf   = (u16*)(ws + 89 * MB);    // 16 MB
    float* vatt  = (float*)(ws + 105 * MB); // 32 MB fp32 (pre-LN1)
    u16*   ln1bf = (u16*)(ws + 137 * MB);   // 16 MB LN1 out

    const int NT = BB * SS;   // 8192 tokens

    // --- one-time converts / weight transposes (bf16, k-innermost) ---
    cvt_bf<<<8192, 256, 0, stream>>>(X, Xbf, NT * EE / 4);
    transp_bf<<<dim3(16, 1, 16), 256, 0, stream>>>(WQ, WQT, EE, DD);
    transp_bf<<<dim3(16, 1, 16), 256, 0, stream>>>(WK, WKT, EE, DD);
    transp_bf<<<dim3(16, 1, 16), 256, 0, stream>>>(WV, WVT, EE, DD);
    transp_bf<<<dim3(16, 16, 1), 256, 0, stream>>>(WO, WOT, HH * DD, EE);
    transp_bf<<<dim3(16, 64, 1), 256, 0, stream>>>(W1, W1T, EE, FF);
    transp_bf<<<dim3(64, 16, 1), 256, 0, stream>>>(W2, W2T, FF, EE);

    // --- projections (Q,K normal layout; V produced transposed) ---
    gemm_bf16<0><<<dim3(64, 8), 256, 0, stream>>>(Xbf, WQT, EE, 1024, Qbf, nullptr, nullptr);
    gemm_bf16<0><<<dim3(64, 8), 256, 0, stream>>>(Xbf, WKT, EE, 1024, Kbf, nullptr, nullptr);
    gemm_bf16<0><<<dim3(8, 64), 256, 0, stream>>>(WVT, Xbf, EE, 8192, Vt, nullptr, nullptr);

    // --- attention (column softmax then /8), fused path ---
    stats_l<<<dim3(SS / 128, BB * HH), 256, 0, stream>>>(Qbf, Kbf, Ls);
    vscale<<<dim3(1024, BB), 256, 0, stream>>>(Vt, Ls);
    pv_fused<<<dim3(SS / 128, BB * HH), 256, 0, stream>>>(Qbf, Kbf, Vt, vecbf);

    // --- WO + residual X -> vatt (fp32), LN1 -> ln1bf ---
    gemm_bf16<1><<<dim3(64, 8), 256, 0, stream>>>(vecbf, WOT, EE, 1024, vatt, nullptr, X);
    ln_bf_kernel<<<NT, 256, 0, stream>>>(vatt, gamma, beta, ln1bf);

    // --- FFN ---
    gemm_bf16<2><<<dim3(64, 32), 256, 0, stream>>>(ln1bf, W1T, EE, FF, hid, b1, nullptr);
    gemm_bf16<3><<<dim3(64, 8), 256, 0, stream>>>(hid, W2T, FF, 1024, out, b2, ln1bf);

    // --- final LN in place on d_out ---
    ln_kernel<<<NT, 256, 0, stream>>>(out, gamma, beta);
}